// Round 4
// baseline (664.040 us; speedup 1.0000x reference)
//
#include <hip/hip_runtime.h>
#include <hip/hip_bf16.h>
#include <math.h>

#define SEQ    2048
#define HIDDEN 4096
#define NH     32
#define NKV    8
#define HD     128
#define QKV_N  6144   // 4096 q + 1024 k + 1024 v

typedef __attribute__((ext_vector_type(8))) short bf16x8;
typedef __attribute__((ext_vector_type(4))) float f32x4;
typedef unsigned short u16;

__device__ inline void gl_lds16(const void* g, void* lds) {
  __builtin_amdgcn_global_load_lds((const __attribute__((address_space(1))) void*)g,
                                   (__attribute__((address_space(3))) void*)lds, 16, 0, 0);
}

__device__ inline u16 f2bf(float f) {
  __hip_bfloat16 h = __float2bfloat16(f);
  return *(u16*)&h;
}
__device__ inline float bf2f(u16 u) {
  __hip_bfloat16 h = *(__hip_bfloat16*)&u;
  return __bfloat162float(h);
}

// ---------------- fp32 -> bf16 conversion (8 elements / thread) ----------------
__global__ void cvt_f32_bf16(const float* __restrict__ src, u16* __restrict__ dst, int n8) {
  int i = blockIdx.x * blockDim.x + threadIdx.x;
  if (i >= n8) return;
  const float4* s = (const float4*)src + (size_t)i * 2;
  float4 a = s[0], b = s[1];
  float v[8] = {a.x, a.y, a.z, a.w, b.x, b.y, b.z, b.w};
  union { u16 o[8]; uint4 u; } pk;
#pragma unroll
  for (int j = 0; j < 8; j++) pk.o[j] = f2bf(v[j]);
  *(uint4*)(dst + (size_t)i * 8) = pk.u;
}

// ---------------- bf16 GEMM, C = A * B^T  (A: MxK, B: NxK, both row-major) ----------------
template <int OUTF32>
__global__ __launch_bounds__(256) void gemm_bt(const u16* __restrict__ A,
                                               const u16* __restrict__ B,
                                               void* __restrict__ Cout,
                                               int M, int N, int K) {
  __shared__ __align__(16) u16 As[128 * 32];
  __shared__ __align__(16) u16 Bs[128 * 32];
  const int tid = threadIdx.x;
  const int wave = tid >> 6, lane = tid & 63;
  const int quad = lane >> 4, l16 = lane & 15;
  const int wm = wave >> 1, wn = wave & 1;
  const int m0 = blockIdx.y * 128, n0 = blockIdx.x * 128;

  f32x4 acc[4][4] = {};
  const int lrow = lane >> 2;
  const int kchunk = (lane & 3) * 8;

  for (int k0 = 0; k0 < K; k0 += 32) {
    __syncthreads();
#pragma unroll
    for (int i = 0; i < 2; i++) {
      int r = wave * 32 + i * 16 + lrow;
      gl_lds16(A + (size_t)(m0 + r) * K + k0 + kchunk, &As[(wave * 32 + i * 16) * 32]);
      gl_lds16(B + (size_t)(n0 + r) * K + k0 + kchunk, &Bs[(wave * 32 + i * 16) * 32]);
    }
    __syncthreads();
    bf16x8 af[4], bfr[4];
#pragma unroll
    for (int t = 0; t < 4; t++) {
      af[t]  = *(const bf16x8*)&As[(wm * 64 + t * 16 + l16) * 32 + quad * 8];
      bfr[t] = *(const bf16x8*)&Bs[(wn * 64 + t * 16 + l16) * 32 + quad * 8];
    }
#pragma unroll
    for (int mt = 0; mt < 4; mt++)
#pragma unroll
      for (int nt = 0; nt < 4; nt++)
        acc[mt][nt] = __builtin_amdgcn_mfma_f32_16x16x32_bf16(af[mt], bfr[nt], acc[mt][nt], 0, 0, 0);
  }

#pragma unroll
  for (int mt = 0; mt < 4; mt++)
#pragma unroll
    for (int nt = 0; nt < 4; nt++)
#pragma unroll
      for (int r = 0; r < 4; r++) {
        int row = m0 + wm * 64 + mt * 16 + quad * 4 + r;
        int col = n0 + wn * 64 + nt * 16 + l16;
        float v = acc[mt][nt][r];
        if (OUTF32) ((float*)Cout)[(size_t)row * N + col] = v;
        else        ((u16*)Cout)[(size_t)row * N + col] = f2bf(v);
      }
}

// ---------------- RoPE in-place on bf16 qkv buffer (q heads 0..31, k heads 0..7) ------------
__global__ void rope_kernel(u16* __restrict__ qkv, const int* __restrict__ pos_ids) {
  int idx = blockIdx.x * blockDim.x + threadIdx.x;
  int d = idx & 63;
  int h = (idx >> 6) % 40;
  int s = idx / (64 * 40);
  if (s >= SEQ) return;
  int off = (h < NH) ? h * HD : HIDDEN + (h - NH) * HD;
  u16* base = qkv + (size_t)s * QKV_N + off;
  float inv_freq = powf(10000.0f, -(float)d * (1.0f / 64.0f));
  float ang = (float)pos_ids[s] * inv_freq;
  float sn, cs;
  sincosf(ang, &sn, &cs);
  float x1 = bf2f(base[d]);
  float x2 = bf2f(base[d + 64]);
  base[d]      = f2bf(x1 * cs - x2 * sn);
  base[d + 64] = f2bf(x2 * cs + x1 * sn);
}

// ---------------- V transpose: qkv v-slice [s][c] -> vt[c][s]  (c = kvh*128+d, 1024 x 2048) --
__global__ __launch_bounds__(256) void transpose_v(const u16* __restrict__ qkv,
                                                   u16* __restrict__ vt) {
  __shared__ u16 t[64][72];
  const int s0 = blockIdx.x * 64, c0 = blockIdx.y * 64;
  const int tid = threadIdx.x;
#pragma unroll
  for (int i = 0; i < 2; i++) {
    int r = (tid >> 3) + i * 32;
    int c = (tid & 7) * 8;
    *(uint4*)&t[r][c] = *(const uint4*)&qkv[(size_t)(s0 + r) * QKV_N + 5120 + c0 + c];
  }
  __syncthreads();
#pragma unroll
  for (int i = 0; i < 2; i++) {
    int c = (tid >> 3) + i * 32;
    int s = (tid & 7) * 8;
    union { uint4 u; u16 e[8]; } o;
#pragma unroll
    for (int j = 0; j < 8; j++) o.e[j] = t[s + j][c];
    *(uint4*)&vt[(size_t)(c0 + c) * SEQ + s0 + s] = o.u;
  }
}

// ---------------- flash attention v4: XCD-kvh affinity, 1 wave/block, fixed-M softmax -------
// Block = 1 wave (64 threads) owning 32 q-rows of one head. kvh = blk & 7 so that,
// under round-robin block->XCD dispatch, each XCD touches exactly one kv-head:
// K+V working set 1 MB -> resident in that XCD's 4 MB L2. Longest q-tiles first.
// Fixed softmax shift (exp2(s*c-32)) keeps the loop shuffle-free; no barriers at all.
#define PS_STRIDE 72   // u16 units; 144B rows
__global__ __launch_bounds__(64) void attn_kernel(const u16* __restrict__ qkv,
                                                  const u16* __restrict__ vt,
                                                  u16* __restrict__ attn_out) {
  __shared__ __align__(16) u16 Ps[32 * PS_STRIDE];
  const int blk = blockIdx.x;
  const int kvh = blk & 7;             // XCD affinity: one kv-head per XCD
  const int rest = blk >> 3;           // 0..255 = 64 q-tiles x 4 heads-in-group
  const int hg = rest & 3;
  const int it = 63 - (rest >> 2);     // longest q-tiles dispatched first
  const int h  = kvh * 4 + hg;
  const int lane = threadIdx.x & 63;
  const int quad = lane >> 4, l16 = lane & 15;
  const int q0 = it * 32;

  const float c = 0.08838834764831845f * 1.4426950408889634f; // D^-0.5 * log2e

  // Q fragments: A-layout, 2 m-tiles x 4 d-chunks
  bf16x8 qf[2][4];
#pragma unroll
  for (int m = 0; m < 2; m++)
#pragma unroll
    for (int dc = 0; dc < 4; dc++)
      qf[m][dc] = *(const bf16x8*)(qkv + (size_t)(q0 + m * 16 + l16) * QKV_N + h * HD + dc * 32 + quad * 8);

  // K row pointers per st subtile
  const u16* kp[4];
#pragma unroll
  for (int st = 0; st < 4; st++)
    kp[st] = qkv + (size_t)(st * 16 + l16) * QKV_N + HIDDEN + kvh * HD + quad * 8;
  // V^T row pointers per dt subtile
  const u16* vp[8];
#pragma unroll
  for (int dt = 0; dt < 8; dt++)
    vp[dt] = vt + (size_t)(kvh * HD + dt * 16 + l16) * SEQ + quad * 8;

  float lsum[2][4] = {};
  f32x4 o[2][8] = {};

  const int n_kt = (q0 + 95) >> 6;   // 64-key tiles covering 0 .. q0+31
  for (int kt = 0; kt < n_kt; kt++) {
    const bool last = (kt == n_kt - 1);

    // ---- S = Q K^T over 64 keys ----
    f32x4 s[2][4] = {};
#pragma unroll
    for (int st = 0; st < 4; st++) {
      bf16x8 kst[4];
#pragma unroll
      for (int dc = 0; dc < 4; dc++) kst[dc] = *(const bf16x8*)(kp[st] + dc * 32);
#pragma unroll
      for (int dc = 0; dc < 4; dc++)
#pragma unroll
        for (int m = 0; m < 2; m++)
          s[m][st] = __builtin_amdgcn_mfma_f32_16x16x32_bf16(qf[m][dc], kst[dc], s[m][st], 0, 0, 0);
    }

    // ---- fixed-shift softmax: p = exp2(s*c - 32); accumulate l per-lane ----
#pragma unroll
    for (int m = 0; m < 2; m++)
#pragma unroll
      for (int r = 0; r < 4; r++) {
#pragma unroll
        for (int st = 0; st < 4; st++) {
          float v = fmaf(s[m][st][r], c, -32.0f);
          if (last) {
            int key = kt * 64 + st * 16 + l16;
            int row = q0 + m * 16 + quad * 4 + r;
            if (key > row) v = -1e30f;
          }
          float p = exp2f(v);
          s[m][st][r] = p;
          lsum[m][r] += p;
          Ps[(m * 16 + quad * 4 + r) * PS_STRIDE + st * 16 + l16] = f2bf(p);
        }
      }

    // ---- P A-fragments ----
    bf16x8 pf[2][2];
#pragma unroll
    for (int m = 0; m < 2; m++)
#pragma unroll
      for (int kc = 0; kc < 2; kc++)
        pf[m][kc] = *(const bf16x8*)&Ps[(m * 16 + l16) * PS_STRIDE + kc * 32 + quad * 8];

    // ---- O += P V ----
#pragma unroll
    for (int dt = 0; dt < 8; dt++) {
      bf16x8 vf0 = *(const bf16x8*)(vp[dt]);
      bf16x8 vf1 = *(const bf16x8*)(vp[dt] + 32);
#pragma unroll
      for (int m = 0; m < 2; m++) {
        o[m][dt] = __builtin_amdgcn_mfma_f32_16x16x32_bf16(pf[m][0], vf0, o[m][dt], 0, 0, 0);
        o[m][dt] = __builtin_amdgcn_mfma_f32_16x16x32_bf16(pf[m][1], vf1, o[m][dt], 0, 0, 0);
      }
    }

#pragma unroll
    for (int st = 0; st < 4; st++) kp[st] += (size_t)64 * QKV_N;
#pragma unroll
    for (int dt = 0; dt < 8; dt++) vp[dt] += 64;
  }

  // ---- l reduce over the 16 column lanes, then store ----
#pragma unroll
  for (int m = 0; m < 2; m++)
#pragma unroll
    for (int r = 0; r < 4; r++) {
#pragma unroll
      for (int off = 1; off < 16; off <<= 1)
        lsum[m][r] += __shfl_xor(lsum[m][r], off);
      lsum[m][r] = 1.0f / lsum[m][r];
    }

#pragma unroll
  for (int m = 0; m < 2; m++)
#pragma unroll
    for (int dt = 0; dt < 8; dt++)
#pragma unroll
      for (int r = 0; r < 4; r++) {
        int row = q0 + m * 16 + quad * 4 + r;
        attn_out[(size_t)row * HIDDEN + h * HD + dt * 16 + l16] = f2bf(o[m][dt][r] * lsum[m][r]);
      }
}

// ---------------- launch ----------------
extern "C" void kernel_launch(void* const* d_in, const int* in_sizes, int n_in,
                              void* d_out, int out_size, void* d_ws, size_t ws_size,
                              hipStream_t stream) {
  const float* x  = (const float*)d_in[0];
  const int* pos  = (const int*)d_in[1];
  const float* Wq = (const float*)d_in[3];
  const float* Wk = (const float*)d_in[4];
  const float* Wv = (const float*)d_in[5];
  const float* Wo = (const float*)d_in[6];
  float* out = (float*)d_out;

  u16* x_bf    = (u16*)d_ws;                                  // 2048*4096
  u16* Wqkv_bf = x_bf + (size_t)SEQ * HIDDEN;                 // 6144*4096
  u16* qkv_bf  = Wqkv_bf + (size_t)QKV_N * HIDDEN;            // 2048*6144
  u16* attn_bf = qkv_bf + (size_t)SEQ * QKV_N;                // 2048*4096
  u16* Wo_bf   = attn_bf + (size_t)SEQ * HIDDEN;              // 4096*4096
  u16* vt_bf   = x_bf;   // reuse x_bf region (dead after gemm1); 1024*2048 fits

  auto cvt = [&](const float* s, u16* d, size_t n) {
    int n8 = (int)(n / 8);
    cvt_f32_bf16<<<(n8 + 255) / 256, 256, 0, stream>>>(s, d, n8);
  };
  cvt(x,  x_bf,    (size_t)SEQ * HIDDEN);
  cvt(Wq, Wqkv_bf,                         (size_t)4096 * 4096);
  cvt(Wk, Wqkv_bf + (size_t)4096 * 4096,   (size_t)1024 * 4096);
  cvt(Wv, Wqkv_bf + (size_t)5120 * 4096,   (size_t)1024 * 4096);
  cvt(Wo, Wo_bf,   (size_t)4096 * 4096);

  dim3 g1(QKV_N / 128, SEQ / 128);
  gemm_bt<0><<<g1, 256, 0, stream>>>(x_bf, Wqkv_bf, qkv_bf, SEQ, QKV_N, HIDDEN);

  int rope_threads = SEQ * 40 * 64;
  rope_kernel<<<rope_threads / 256, 256, 0, stream>>>(qkv_bf, pos);

  dim3 gt(SEQ / 64, 1024 / 64);
  transpose_v<<<gt, 256, 0, stream>>>(qkv_bf, vt_bf);

  attn_kernel<<<2048, 64, 0, stream>>>(qkv_bf, vt_bf, attn_bf);

  dim3 g3(HIDDEN / 128, SEQ / 128);
  gemm_bt<1><<<g3, 256, 0, stream>>>(attn_bf, Wo_bf, out, SEQ, HIDDEN, HIDDEN);
}

// Round 5
// 639.485 us; speedup vs baseline: 1.0384x; 1.0384x over previous
//
#include <hip/hip_runtime.h>
#include <hip/hip_bf16.h>
#include <math.h>

#define SEQ    2048
#define HIDDEN 4096
#define NH     32
#define NKV    8
#define HD     128
#define QKV_N  6144   // 4096 q + 1024 k + 1024 v

typedef __attribute__((ext_vector_type(8))) short bf16x8;
typedef __attribute__((ext_vector_type(4))) float f32x4;
typedef unsigned short u16;
typedef unsigned int u32;

__device__ inline void gl_lds16(const void* g, void* lds) {
  __builtin_amdgcn_global_load_lds((const __attribute__((address_space(1))) void*)g,
                                   (__attribute__((address_space(3))) void*)lds, 16, 0, 0);
}

__device__ inline u16 f2bf(float f) {
  __hip_bfloat16 h = __float2bfloat16(f);
  return *(u16*)&h;
}
__device__ inline float bf2f(u16 u) {
  __hip_bfloat16 h = *(__hip_bfloat16*)&u;
  return __bfloat162float(h);
}

// ---------------- fp32 -> bf16 conversion (8 elements / thread) ----------------
__global__ void cvt_f32_bf16(const float* __restrict__ src, u16* __restrict__ dst, int n8) {
  int i = blockIdx.x * blockDim.x + threadIdx.x;
  if (i >= n8) return;
  const float4* s = (const float4*)src + (size_t)i * 2;
  float4 a = s[0], b = s[1];
  float v[8] = {a.x, a.y, a.z, a.w, b.x, b.y, b.z, b.w};
  union { u16 o[8]; uint4 u; } pk;
#pragma unroll
  for (int j = 0; j < 8; j++) pk.o[j] = f2bf(v[j]);
  *(uint4*)(dst + (size_t)i * 8) = pk.u;
}

// ---------------- bf16 GEMM, C = A * B^T  (A: MxK, B: NxK, both row-major) ----------------
template <int OUTF32>
__global__ __launch_bounds__(256) void gemm_bt(const u16* __restrict__ A,
                                               const u16* __restrict__ B,
                                               void* __restrict__ Cout,
                                               int M, int N, int K) {
  __shared__ __align__(16) u16 As[128 * 32];
  __shared__ __align__(16) u16 Bs[128 * 32];
  const int tid = threadIdx.x;
  const int wave = tid >> 6, lane = tid & 63;
  const int quad = lane >> 4, l16 = lane & 15;
  const int wm = wave >> 1, wn = wave & 1;
  const int m0 = blockIdx.y * 128, n0 = blockIdx.x * 128;

  f32x4 acc[4][4] = {};
  const int lrow = lane >> 2;
  const int kchunk = (lane & 3) * 8;

  for (int k0 = 0; k0 < K; k0 += 32) {
    __syncthreads();
#pragma unroll
    for (int i = 0; i < 2; i++) {
      int r = wave * 32 + i * 16 + lrow;
      gl_lds16(A + (size_t)(m0 + r) * K + k0 + kchunk, &As[(wave * 32 + i * 16) * 32]);
      gl_lds16(B + (size_t)(n0 + r) * K + k0 + kchunk, &Bs[(wave * 32 + i * 16) * 32]);
    }
    __syncthreads();
    bf16x8 af[4], bfr[4];
#pragma unroll
    for (int t = 0; t < 4; t++) {
      af[t]  = *(const bf16x8*)&As[(wm * 64 + t * 16 + l16) * 32 + quad * 8];
      bfr[t] = *(const bf16x8*)&Bs[(wn * 64 + t * 16 + l16) * 32 + quad * 8];
    }
#pragma unroll
    for (int mt = 0; mt < 4; mt++)
#pragma unroll
      for (int nt = 0; nt < 4; nt++)
        acc[mt][nt] = __builtin_amdgcn_mfma_f32_16x16x32_bf16(af[mt], bfr[nt], acc[mt][nt], 0, 0, 0);
  }

#pragma unroll
  for (int mt = 0; mt < 4; mt++)
#pragma unroll
    for (int nt = 0; nt < 4; nt++)
#pragma unroll
      for (int r = 0; r < 4; r++) {
        int row = m0 + wm * 64 + mt * 16 + quad * 4 + r;
        int col = n0 + wn * 64 + nt * 16 + l16;
        float v = acc[mt][nt][r];
        if (OUTF32) ((float*)Cout)[(size_t)row * N + col] = v;
        else        ((u16*)Cout)[(size_t)row * N + col] = f2bf(v);
      }
}

// ---------------- RoPE in-place on bf16 qkv buffer (q heads 0..31, k heads 0..7) ------------
__global__ void rope_kernel(u16* __restrict__ qkv, const int* __restrict__ pos_ids) {
  int idx = blockIdx.x * blockDim.x + threadIdx.x;
  int d = idx & 63;
  int h = (idx >> 6) % 40;
  int s = idx / (64 * 40);
  if (s >= SEQ) return;
  int off = (h < NH) ? h * HD : HIDDEN + (h - NH) * HD;
  u16* base = qkv + (size_t)s * QKV_N + off;
  float inv_freq = powf(10000.0f, -(float)d * (1.0f / 64.0f));
  float ang = (float)pos_ids[s] * inv_freq;
  float sn, cs;
  sincosf(ang, &sn, &cs);
  float x1 = bf2f(base[d]);
  float x2 = bf2f(base[d + 64]);
  base[d]      = f2bf(x1 * cs - x2 * sn);
  base[d + 64] = f2bf(x2 * cs + x1 * sn);
}

// ---------------- V transpose: qkv v-slice [s][c] -> vt[c][s]  (c = kvh*128+d, 1024 x 2048) --
__global__ __launch_bounds__(256) void transpose_v(const u16* __restrict__ qkv,
                                                   u16* __restrict__ vt) {
  __shared__ u16 t[64][72];
  const int s0 = blockIdx.x * 64, c0 = blockIdx.y * 64;
  const int tid = threadIdx.x;
#pragma unroll
  for (int i = 0; i < 2; i++) {
    int r = (tid >> 3) + i * 32;
    int c = (tid & 7) * 8;
    *(uint4*)&t[r][c] = *(const uint4*)&qkv[(size_t)(s0 + r) * QKV_N + 5120 + c0 + c];
  }
  __syncthreads();
#pragma unroll
  for (int i = 0; i < 2; i++) {
    int c = (tid >> 3) + i * 32;
    int s = (tid & 7) * 8;
    union { uint4 u; u16 e[8]; } o;
#pragma unroll
    for (int j = 0; j < 8; j++) o.e[j] = t[s + j][c];
    *(uint4*)&vt[(size_t)(c0 + c) * SEQ + s0 + s] = o.u;
  }
}

// ---------------- flash attention v5: S^T form, shuffle-based P transform, split-K ----------
// Block = 2 waves on the same (32 q-rows, head); wave 0 even key-tiles, wave 1 odd.
// S^T = K*Q^T (mfma A=K, B=Q) -> C-layout col=q(l16), row=key(quad*4+r).
// P^T enters PV as B-operand via quad-permutation (__shfl), NO LDS in the loop.
// O^T = V^T*P^T accumulated in C-layout (col=q). Fixed softmax shift exp2(s*c-32):
// partials combine by pure addition. Only the epilogue combine uses LDS + 1 barrier.
// kvh = blk&7 keeps one kv-head per XCD (L2 affinity); longest q-tiles first.
__global__ __launch_bounds__(128, 3) void attn_kernel(const u16* __restrict__ qkv,
                                                      const u16* __restrict__ vt,
                                                      u16* __restrict__ attn_out) {
  __shared__ __align__(16) float Ex[32 * 132];   // [q:32][d:128 +pad] + col128 = lsum
  const int blk = blockIdx.x;
  const int kvh = blk & 7;             // XCD affinity: one kv-head per XCD
  const int hg = (blk >> 3) & 3;
  const int it = 63 - (blk >> 5);      // longest q-tiles dispatched first
  const int h  = kvh * 4 + hg;
  const int tid = threadIdx.x;
  const int wave = tid >> 6, lane = tid & 63;
  const int quad = lane >> 4, l16 = lane & 15;
  const int q0 = it * 32;

  const float c = 0.08838834764831845f * 1.4426950408889634f; // D^-0.5 * log2e

  // Q B-fragments: n=q(l16), k=d(quad*8+j); 2 m-tiles x 4 d-chunks
  bf16x8 qf[2][4];
#pragma unroll
  for (int m = 0; m < 2; m++)
#pragma unroll
    for (int dc = 0; dc < 4; dc++)
      qf[m][dc] = *(const bf16x8*)(qkv + (size_t)(q0 + m * 16 + l16) * QKV_N + h * HD + dc * 32 + quad * 8);

  // K A-fragment pointers: m=key(st*16+l16), k=d; start at this wave's first tile
  const u16* kp[4];
#pragma unroll
  for (int st = 0; st < 4; st++)
    kp[st] = qkv + (size_t)(wave * 64 + st * 16 + l16) * QKV_N + HIDDEN + kvh * HD + quad * 8;
  // V^T A-fragment pointers: m=d(dt*16+l16), k=key
  const u16* vp[8];
#pragma unroll
  for (int dt = 0; dt < 8; dt++)
    vp[dt] = vt + (size_t)(kvh * HD + dt * 16 + l16) * SEQ + wave * 64 + quad * 8;

  float lsum[2] = {0.f, 0.f};
  f32x4 o[2][8] = {};

  const int srcA = ((lane >> 4) & 1) * 32 + l16;   // quad 0 or 2, same l16
  const int srcB = srcA + 16;                      // quad 1 or 3
  const bool hi = quad >= 2;

  const int n_kt = (q0 + 95) >> 6;   // 64-key tiles covering 0 .. q0+31
  for (int kt = wave; kt < n_kt; kt += 2) {
    const bool last = (kt == n_kt - 1);

    // ---- S^T = K Q^T over 64 keys; softmax + pack to bf16 pairs ----
    u32 pk[2][4][2];
#pragma unroll
    for (int st = 0; st < 4; st++) {
      bf16x8 kst[4];
#pragma unroll
      for (int dc = 0; dc < 4; dc++) kst[dc] = *(const bf16x8*)(kp[st] + dc * 32);
      f32x4 s[2] = {};
#pragma unroll
      for (int dc = 0; dc < 4; dc++)
#pragma unroll
        for (int m = 0; m < 2; m++)
          s[m] = __builtin_amdgcn_mfma_f32_16x16x32_bf16(kst[dc], qf[m][dc], s[m], 0, 0, 0);
#pragma unroll
      for (int m = 0; m < 2; m++) {
        float pr[4];
#pragma unroll
        for (int r = 0; r < 4; r++) {
          float v = fmaf(s[m][r], c, -32.0f);
          if (last) {
            int key = kt * 64 + st * 16 + quad * 4 + r;
            if (key > q0 + m * 16 + l16) v = -1e30f;
          }
          pr[r] = exp2f(v);
          lsum[m] += pr[r];
        }
        pk[m][st][0] = ((u32)f2bf(pr[1]) << 16) | f2bf(pr[0]);
        pk[m][st][1] = ((u32)f2bf(pr[3]) << 16) | f2bf(pr[2]);
      }
    }

    // ---- P^T B-fragments via quad permutation (no LDS) ----
    bf16x8 pf[2][2];
#pragma unroll
    for (int m = 0; m < 2; m++)
#pragma unroll
      for (int kc = 0; kc < 2; kc++) {
        union { u32 w[4]; bf16x8 v; } u;
        u32 a0 = (u32)__shfl((int)pk[m][2 * kc][0],     srcA);
        u32 b0 = (u32)__shfl((int)pk[m][2 * kc + 1][0], srcA);
        u32 a1 = (u32)__shfl((int)pk[m][2 * kc][1],     srcA);
        u32 b1 = (u32)__shfl((int)pk[m][2 * kc + 1][1], srcA);
        u32 a2 = (u32)__shfl((int)pk[m][2 * kc][0],     srcB);
        u32 b2 = (u32)__shfl((int)pk[m][2 * kc + 1][0], srcB);
        u32 a3 = (u32)__shfl((int)pk[m][2 * kc][1],     srcB);
        u32 b3 = (u32)__shfl((int)pk[m][2 * kc + 1][1], srcB);
        u.w[0] = hi ? b0 : a0;
        u.w[1] = hi ? b1 : a1;
        u.w[2] = hi ? b2 : a2;
        u.w[3] = hi ? b3 : a3;
        pf[m][kc] = u.v;
      }

    // ---- O^T += V^T P^T ----
#pragma unroll
    for (int dt = 0; dt < 8; dt++) {
      bf16x8 vf0 = *(const bf16x8*)(vp[dt]);
      bf16x8 vf1 = *(const bf16x8*)(vp[dt] + 32);
#pragma unroll
      for (int m = 0; m < 2; m++) {
        o[m][dt] = __builtin_amdgcn_mfma_f32_16x16x32_bf16(vf0, pf[m][0], o[m][dt], 0, 0, 0);
        o[m][dt] = __builtin_amdgcn_mfma_f32_16x16x32_bf16(vf1, pf[m][1], o[m][dt], 0, 0, 0);
      }
    }

#pragma unroll
    for (int st = 0; st < 4; st++) kp[st] += (size_t)128 * QKV_N;   // skip 2 tiles
#pragma unroll
    for (int dt = 0; dt < 8; dt++) vp[dt] += 128;
  }

  // ---- reduce lsum across the 4 quads (q is per-lane l16) ----
#pragma unroll
  for (int m = 0; m < 2; m++) {
    lsum[m] += __shfl_xor(lsum[m], 16);
    lsum[m] += __shfl_xor(lsum[m], 32);
  }

  // ---- combine the two waves' partials (pure addition; fixed shift) ----
  if (wave == 1) {
#pragma unroll
    for (int m = 0; m < 2; m++) {
#pragma unroll
      for (int dt = 0; dt < 8; dt++)
        *(f32x4*)&Ex[(m * 16 + l16) * 132 + dt * 16 + quad * 4] = o[m][dt];
      if (lane < 16) Ex[(m * 16 + l16) * 132 + 128] = lsum[m];
    }
  }
  __syncthreads();
  if (wave == 0) {
#pragma unroll
    for (int m = 0; m < 2; m++) {
      float lt = lsum[m] + Ex[(m * 16 + l16) * 132 + 128];
      float inv = 1.0f / lt;
      size_t base = (size_t)(q0 + m * 16 + l16) * HIDDEN + h * HD;
#pragma unroll
      for (int dt = 0; dt < 8; dt++) {
        f32x4 p = *(const f32x4*)&Ex[(m * 16 + l16) * 132 + dt * 16 + quad * 4];
        float v0 = (o[m][dt][0] + p[0]) * inv;
        float v1 = (o[m][dt][1] + p[1]) * inv;
        float v2 = (o[m][dt][2] + p[2]) * inv;
        float v3 = (o[m][dt][3] + p[3]) * inv;
        u32 w0 = ((u32)f2bf(v1) << 16) | f2bf(v0);
        u32 w1 = ((u32)f2bf(v3) << 16) | f2bf(v2);
        uint2 wv; wv.x = w0; wv.y = w1;
        *(uint2*)&attn_out[base + dt * 16 + quad * 4] = wv;
      }
    }
  }
}

// ---------------- launch ----------------
extern "C" void kernel_launch(void* const* d_in, const int* in_sizes, int n_in,
                              void* d_out, int out_size, void* d_ws, size_t ws_size,
                              hipStream_t stream) {
  const float* x  = (const float*)d_in[0];
  const int* pos  = (const int*)d_in[1];
  const float* Wq = (const float*)d_in[3];
  const float* Wk = (const float*)d_in[4];
  const float* Wv = (const float*)d_in[5];
  const float* Wo = (const float*)d_in[6];
  float* out = (float*)d_out;

  u16* x_bf    = (u16*)d_ws;                                  // 2048*4096
  u16* Wqkv_bf = x_bf + (size_t)SEQ * HIDDEN;                 // 6144*4096
  u16* qkv_bf  = Wqkv_bf + (size_t)QKV_N * HIDDEN;            // 2048*6144
  u16* attn_bf = qkv_bf + (size_t)SEQ * QKV_N;                // 2048*4096
  u16* Wo_bf   = attn_bf + (size_t)SEQ * HIDDEN;              // 4096*4096
  u16* vt_bf   = x_bf;   // reuse x_bf region (dead after gemm1); 1024*2048 fits

  auto cvt = [&](const float* s, u16* d, size_t n) {
    int n8 = (int)(n / 8);
    cvt_f32_bf16<<<(n8 + 255) / 256, 256, 0, stream>>>(s, d, n8);
  };
  cvt(x,  x_bf,    (size_t)SEQ * HIDDEN);
  cvt(Wq, Wqkv_bf,                         (size_t)4096 * 4096);
  cvt(Wk, Wqkv_bf + (size_t)4096 * 4096,   (size_t)1024 * 4096);
  cvt(Wv, Wqkv_bf + (size_t)5120 * 4096,   (size_t)1024 * 4096);
  cvt(Wo, Wo_bf,   (size_t)4096 * 4096);

  dim3 g1(QKV_N / 128, SEQ / 128);
  gemm_bt<0><<<g1, 256, 0, stream>>>(x_bf, Wqkv_bf, qkv_bf, SEQ, QKV_N, HIDDEN);

  int rope_threads = SEQ * 40 * 64;
  rope_kernel<<<rope_threads / 256, 256, 0, stream>>>(qkv_bf, pos);

  dim3 gt(SEQ / 64, 1024 / 64);
  transpose_v<<<gt, 256, 0, stream>>>(qkv_bf, vt_bf);

  attn_kernel<<<2048, 128, 0, stream>>>(qkv_bf, vt_bf, attn_bf);

  dim3 g3(HIDDEN / 128, SEQ / 128);
  gemm_bt<1><<<g3, 256, 0, stream>>>(attn_bf, Wo_bf, out, SEQ, HIDDEN, HIDDEN);
}